// Round 1
// baseline (2491.127 us; speedup 1.0000x reference)
//
#include <hip/hip_runtime.h>
#include <math.h>

#define FEAT 128
#define HID  64

// ---------------- degree / norm ----------------

__global__ void init_deg_k(float* deg, int n) {
    int i = blockIdx.x * blockDim.x + threadIdx.x;
    if (i < n) deg[i] = 1.0f;   // self-loop contributes 1
}

__global__ void deg_accum_k(const int* __restrict__ dst, float* deg, int e) {
    int i = blockIdx.x * blockDim.x + threadIdx.x;
    if (i < e) atomicAdd(&deg[dst[i]], 1.0f);
}

__global__ void dinv_k(float* deg, int n) {
    int i = blockIdx.x * blockDim.x + threadIdx.x;
    if (i < n) deg[i] = 1.0f / sqrtf(deg[i]);   // deg >= 1 always
}

__global__ void norm_k(const int* __restrict__ src, const int* __restrict__ dst,
                       const float* __restrict__ dinv, float* __restrict__ norm, int e) {
    int i = blockIdx.x * blockDim.x + threadIdx.x;
    if (i < e) norm[i] = dinv[src[i]] * dinv[dst[i]];
}

// ---------------- dense transform: out[n,64] = X[n,K] @ W[K,64] ----------------
// One wave per row; lane j computes column j. W staged in LDS (K*64*4 <= 32 KB).
// x values are wave-uniform broadcast loads (all lanes same address).

template<int K>
__global__ void gemm_k(const float* __restrict__ X, const float* __restrict__ W,
                       float* __restrict__ out, int n) {
    __shared__ float sW[K * HID];
    for (int t = threadIdx.x; t < K * HID; t += blockDim.x) sW[t] = W[t];
    __syncthreads();
    int gw   = (int)((blockIdx.x * (size_t)blockDim.x + threadIdx.x) >> 6);
    int lane = threadIdx.x & 63;
    int nw   = (int)((gridDim.x * (size_t)blockDim.x) >> 6);
    for (int row = gw; row < n; row += nw) {
        const float* xr = X + (size_t)row * K;
        float acc = 0.0f;
#pragma unroll
        for (int k = 0; k < K; k += 4) {
            float4 xv = *reinterpret_cast<const float4*>(xr + k);
            acc = fmaf(xv.x, sW[(k + 0) * HID + lane], acc);
            acc = fmaf(xv.y, sW[(k + 1) * HID + lane], acc);
            acc = fmaf(xv.z, sW[(k + 2) * HID + lane], acc);
            acc = fmaf(xv.w, sW[(k + 3) * HID + lane], acc);
        }
        out[(size_t)row * HID + lane] = acc;
    }
}

// ---------------- aggregation ----------------
// out[i][:] initialized with the self-loop term t[i][:]*dinv[i]^2, then
// edges scatter-add t[src][:]*norm[e] into out[dst][:].

__global__ void selfloop_k(const float* __restrict__ t, const float* __restrict__ dinv,
                           float* __restrict__ out, int n) {
    int i = blockIdx.x * blockDim.x + threadIdx.x;
    if (i < n * HID) {
        int node = i >> 6;
        float d = dinv[node];
        out[i] = t[i] * d * d;
    }
}

__global__ void edge_scatter_k(const float* __restrict__ t, const int* __restrict__ src,
                               const int* __restrict__ dst, const float* __restrict__ norm,
                               float* out, int e) {
    int gw   = (int)((blockIdx.x * (size_t)blockDim.x + threadIdx.x) >> 6);
    int lane = threadIdx.x & 63;
    if (gw >= e) return;
    int s = src[gw];
    int d = dst[gw];
    float w = norm[gw];
    float v = t[(size_t)s * HID + lane] * w;
    atomicAdd(&out[(size_t)d * HID + lane], v);
}

__global__ void bias_relu_k(float* h, const float* __restrict__ b, int n) {
    int i = blockIdx.x * blockDim.x + threadIdx.x;
    if (i < n * HID) h[i] = fmaxf(h[i] + b[i & 63], 0.0f);
}

// ---------------- heads ----------------
// One wave per node: logits dot-product (wave reduce) + pooled/count atomics.

__global__ void head_k(const float* __restrict__ h, const float* __restrict__ Wa,
                       const float* __restrict__ ba, const int* __restrict__ batch,
                       float* __restrict__ logits, float* __restrict__ pooled,
                       float* __restrict__ counts, int n) {
    int gw   = (int)((blockIdx.x * (size_t)blockDim.x + threadIdx.x) >> 6);
    int lane = threadIdx.x & 63;
    if (gw >= n) return;
    float v = h[(size_t)gw * HID + lane];
    float p = v * Wa[lane];
#pragma unroll
    for (int off = 32; off > 0; off >>= 1) p += __shfl_down(p, off);
    if (lane == 0) logits[gw] = p + ba[0];
    int g = batch[gw];
    atomicAdd(&pooled[g * HID + lane], v);
    if (lane == 0) atomicAdd(&counts[g], 1.0f);
}

__global__ void value_k(const float* __restrict__ pooled, const float* __restrict__ counts,
                        const float* __restrict__ Wc, const float* __restrict__ bc,
                        float* __restrict__ val, int g) {
    int gw   = (int)((blockIdx.x * (size_t)blockDim.x + threadIdx.x) >> 6);
    int lane = threadIdx.x & 63;
    if (gw >= g) return;
    float cnt = fmaxf(counts[gw], 1.0f);
    float p = (pooled[gw * HID + lane] / cnt) * Wc[lane];
#pragma unroll
    for (int off = 32; off > 0; off >>= 1) p += __shfl_down(p, off);
    if (lane == 0) val[gw] = p + bc[0];
}

extern "C" void kernel_launch(void* const* d_in, const int* in_sizes, int n_in,
                              void* d_out, int out_size, void* d_ws, size_t ws_size,
                              hipStream_t stream) {
    const float* x     = (const float*)d_in[0];
    const int*   ei    = (const int*)d_in[1];
    const int*   batch = (const int*)d_in[2];
    const float* W1    = (const float*)d_in[3];
    const float* b1    = (const float*)d_in[4];
    const float* W2    = (const float*)d_in[5];
    const float* b2    = (const float*)d_in[6];
    const float* Wa    = (const float*)d_in[7];
    const float* ba    = (const float*)d_in[8];
    const float* Wc    = (const float*)d_in[9];
    const float* bc    = (const float*)d_in[10];

    const int n = in_sizes[0] / FEAT;   // 100000
    const int e = in_sizes[1] / 2;      // 1600000
    const int g = out_size - n;         // 64
    const int* src = ei;
    const int* dst = ei + e;

    float* ws     = (float*)d_ws;
    float* deg    = ws;                         // n  (becomes dinv in place)
    float* norm   = deg + n;                    // e
    float* bufA   = norm + e;                   // n*HID
    float* bufB   = bufA + (size_t)n * HID;     // n*HID
    float* pooled = bufB + (size_t)n * HID;     // g*HID
    float* counts = pooled + (size_t)g * HID;   // g

    const int B = 256;
    const int gridN  = (n + B - 1) / B;
    const int gridE  = (e + B - 1) / B;
    const int gridNH = (n * HID + B - 1) / B;
    const int gridEW = (int)(((size_t)e * 64 + B - 1) / B);   // wave per edge
    const int gridNW = (int)(((size_t)n * 64 + B - 1) / B);   // wave per node

    hipMemsetAsync(pooled, 0, (size_t)(g * HID + g) * sizeof(float), stream);

    // norm precompute
    init_deg_k<<<gridN, B, 0, stream>>>(deg, n);
    deg_accum_k<<<gridE, B, 0, stream>>>(dst, deg, e);
    dinv_k<<<gridN, B, 0, stream>>>(deg, n);
    norm_k<<<gridE, B, 0, stream>>>(src, dst, deg, norm, e);

    // layer 1: t1 = x@W1 (bufA); agg into bufB; +b1, relu
    gemm_k<FEAT><<<1024, B, 0, stream>>>(x, W1, bufA, n);
    selfloop_k<<<gridNH, B, 0, stream>>>(bufA, deg, bufB, n);
    edge_scatter_k<<<gridEW, B, 0, stream>>>(bufA, src, dst, norm, bufB, e);
    bias_relu_k<<<gridNH, B, 0, stream>>>(bufB, b1, n);

    // layer 2: t2 = h1@W2 (bufA); agg into bufB; +b2, relu
    gemm_k<HID><<<1024, B, 0, stream>>>(bufB, W2, bufA, n);
    selfloop_k<<<gridNH, B, 0, stream>>>(bufA, deg, bufB, n);
    edge_scatter_k<<<gridEW, B, 0, stream>>>(bufA, src, dst, norm, bufB, e);
    bias_relu_k<<<gridNH, B, 0, stream>>>(bufB, b2, n);

    // heads
    head_k<<<gridNW, B, 0, stream>>>(bufB, Wa, ba, batch, (float*)d_out, pooled, counts, n);
    value_k<<<(g * 64 + B - 1) / B, B, 0, stream>>>(pooled, counts, Wc, bc, (float*)d_out + n, g);
}

// Round 2
// 1878.310 us; speedup vs baseline: 1.3263x; 1.3263x over previous
//
#include <hip/hip_runtime.h>
#include <math.h>

#define FEAT 128
#define HID  64

// ---------------- degree / norm ----------------

__global__ void init_deg_k(float* deg, int n) {
    int i = blockIdx.x * blockDim.x + threadIdx.x;
    if (i < n) deg[i] = 1.0f;   // self-loop contributes 1
}

__global__ void deg_accum_k(const int* __restrict__ dst, float* deg, int e) {
    int i = blockIdx.x * blockDim.x + threadIdx.x;
    if (i < e) atomicAdd(&deg[dst[i]], 1.0f);
}

__global__ void dinv_k(float* deg, int n) {
    int i = blockIdx.x * blockDim.x + threadIdx.x;
    if (i < n) deg[i] = 1.0f / sqrtf(deg[i]);   // deg >= 1 always
}

__global__ void norm_k(const int* __restrict__ src, const int* __restrict__ dst,
                       const float* __restrict__ dinv, float* __restrict__ norm, int e) {
    int i = blockIdx.x * blockDim.x + threadIdx.x;
    if (i < e) norm[i] = dinv[src[i]] * dinv[dst[i]];
}

// ---------------- dense transform: out[n,64] = X[n,K] @ W[K,64] ----------------
// LDS-tiled register-blocked fp32 GEMM. Block = 256 threads computes a
// 64-row x 64-col tile; BK=32 K-chunks; each thread owns a 4x4 register tile.
// All global loads coalesced; LDS reads are float4 with <=2-way bank alias
// (free on gfx950 per m136).

template<int K>
__global__ __launch_bounds__(256, 2) void gemm_tile_k(const float* __restrict__ X,
                                                      const float* __restrict__ W,
                                                      float* __restrict__ out, int n) {
    __shared__ float sX[64][36];   // pad 32->36 keeps float4 align, 2-way alias only
    __shared__ float sW[32][64];
    const int row0 = blockIdx.x * 64;
    const int t  = threadIdx.x;
    const int tx = t & 15;   // col group: cols tx*4 .. tx*4+3
    const int ty = t >> 4;   // row group: rows ty*4 .. ty*4+3

    float acc[4][4] = {};

    for (int k0 = 0; k0 < K; k0 += 32) {
        // stage X tile: 64 rows x 32 floats, 128B-contiguous per 8 lanes
        {
            int r = t >> 3;              // 0..31
            int f = (t & 7) * 4;         // 0,4,..,28
            int gr = row0 + r;
            float4 v = make_float4(0.f, 0.f, 0.f, 0.f);
            if (gr < n) v = *(const float4*)(X + (size_t)gr * K + k0 + f);
            *(float4*)&sX[r][f] = v;
            gr += 32;
            float4 v2 = make_float4(0.f, 0.f, 0.f, 0.f);
            if (gr < n) v2 = *(const float4*)(X + (size_t)gr * K + k0 + f);
            *(float4*)&sX[r + 32][f] = v2;
        }
        // stage W tile: 32 x 64
        {
            int wr = t >> 4;             // 0..15
            int wc = (t & 15) * 4;
            *(float4*)&sW[wr][wc]      = *(const float4*)(W + (size_t)(k0 + wr) * HID + wc);
            *(float4*)&sW[wr + 16][wc] = *(const float4*)(W + (size_t)(k0 + wr + 16) * HID + wc);
        }
        __syncthreads();

#pragma unroll
        for (int k = 0; k < 32; k += 4) {
            float4 a[4], b[4];
#pragma unroll
            for (int i = 0; i < 4; i++) a[i] = *(float4*)&sX[ty * 4 + i][k];
#pragma unroll
            for (int j = 0; j < 4; j++) b[j] = *(float4*)&sW[k + j][tx * 4];
#pragma unroll
            for (int i = 0; i < 4; i++) {
                acc[i][0] = fmaf(a[i].x, b[0].x, acc[i][0]);
                acc[i][1] = fmaf(a[i].x, b[0].y, acc[i][1]);
                acc[i][2] = fmaf(a[i].x, b[0].z, acc[i][2]);
                acc[i][3] = fmaf(a[i].x, b[0].w, acc[i][3]);
                acc[i][0] = fmaf(a[i].y, b[1].x, acc[i][0]);
                acc[i][1] = fmaf(a[i].y, b[1].y, acc[i][1]);
                acc[i][2] = fmaf(a[i].y, b[1].z, acc[i][2]);
                acc[i][3] = fmaf(a[i].y, b[1].w, acc[i][3]);
                acc[i][0] = fmaf(a[i].z, b[2].x, acc[i][0]);
                acc[i][1] = fmaf(a[i].z, b[2].y, acc[i][1]);
                acc[i][2] = fmaf(a[i].z, b[2].z, acc[i][2]);
                acc[i][3] = fmaf(a[i].z, b[2].w, acc[i][3]);
                acc[i][0] = fmaf(a[i].w, b[3].x, acc[i][0]);
                acc[i][1] = fmaf(a[i].w, b[3].y, acc[i][1]);
                acc[i][2] = fmaf(a[i].w, b[3].z, acc[i][2]);
                acc[i][3] = fmaf(a[i].w, b[3].w, acc[i][3]);
            }
        }
        __syncthreads();
    }

#pragma unroll
    for (int i = 0; i < 4; i++) {
        int gr = row0 + ty * 4 + i;
        if (gr < n)
            *(float4*)(out + (size_t)gr * HID + tx * 4) =
                make_float4(acc[i][0], acc[i][1], acc[i][2], acc[i][3]);
    }
}

// ---------------- aggregation ----------------

__global__ void selfloop_k(const float* __restrict__ t, const float* __restrict__ dinv,
                           float* __restrict__ out, int n) {
    int i = blockIdx.x * blockDim.x + threadIdx.x;
    if (i < n * HID) {
        int node = i >> 6;
        float d = dinv[node];
        out[i] = t[i] * d * d;
    }
}

__global__ void edge_scatter_k(const float* __restrict__ t, const int* __restrict__ src,
                               const int* __restrict__ dst, const float* __restrict__ norm,
                               float* out, int e) {
    int gw   = (int)((blockIdx.x * (size_t)blockDim.x + threadIdx.x) >> 6);
    int lane = threadIdx.x & 63;
    if (gw >= e) return;
    int s = src[gw];
    int d = dst[gw];
    float w = norm[gw];
    float v = t[(size_t)s * HID + lane] * w;
    atomicAdd(&out[(size_t)d * HID + lane], v);
}

__global__ void bias_relu_k(float* h, const float* __restrict__ b, int n) {
    int i = blockIdx.x * blockDim.x + threadIdx.x;
    if (i < n * HID) h[i] = fmaxf(h[i] + b[i & 63], 0.0f);
}

// ---------------- heads ----------------

__global__ void head_k(const float* __restrict__ h, const float* __restrict__ Wa,
                       const float* __restrict__ ba, const int* __restrict__ batch,
                       float* __restrict__ logits, float* __restrict__ pooled,
                       float* __restrict__ counts, int n) {
    int gw   = (int)((blockIdx.x * (size_t)blockDim.x + threadIdx.x) >> 6);
    int lane = threadIdx.x & 63;
    if (gw >= n) return;
    float v = h[(size_t)gw * HID + lane];
    float p = v * Wa[lane];
#pragma unroll
    for (int off = 32; off > 0; off >>= 1) p += __shfl_down(p, off);
    if (lane == 0) logits[gw] = p + ba[0];
    int g = batch[gw];
    atomicAdd(&pooled[g * HID + lane], v);
    if (lane == 0) atomicAdd(&counts[g], 1.0f);
}

__global__ void value_k(const float* __restrict__ pooled, const float* __restrict__ counts,
                        const float* __restrict__ Wc, const float* __restrict__ bc,
                        float* __restrict__ val, int g) {
    int gw   = (int)((blockIdx.x * (size_t)blockDim.x + threadIdx.x) >> 6);
    int lane = threadIdx.x & 63;
    if (gw >= g) return;
    float cnt = fmaxf(counts[gw], 1.0f);
    float p = (pooled[gw * HID + lane] / cnt) * Wc[lane];
#pragma unroll
    for (int off = 32; off > 0; off >>= 1) p += __shfl_down(p, off);
    if (lane == 0) val[gw] = p + bc[0];
}

extern "C" void kernel_launch(void* const* d_in, const int* in_sizes, int n_in,
                              void* d_out, int out_size, void* d_ws, size_t ws_size,
                              hipStream_t stream) {
    const float* x     = (const float*)d_in[0];
    const int*   ei    = (const int*)d_in[1];
    const int*   batch = (const int*)d_in[2];
    const float* W1    = (const float*)d_in[3];
    const float* b1    = (const float*)d_in[4];
    const float* W2    = (const float*)d_in[5];
    const float* b2    = (const float*)d_in[6];
    const float* Wa    = (const float*)d_in[7];
    const float* ba    = (const float*)d_in[8];
    const float* Wc    = (const float*)d_in[9];
    const float* bc    = (const float*)d_in[10];

    const int n = in_sizes[0] / FEAT;   // 100000
    const int e = in_sizes[1] / 2;      // 1600000
    const int g = out_size - n;         // 64
    const int* src = ei;
    const int* dst = ei + e;

    float* ws     = (float*)d_ws;
    float* deg    = ws;                         // n  (becomes dinv in place)
    float* norm   = deg + n;                    // e
    float* bufA   = norm + e;                   // n*HID
    float* bufB   = bufA + (size_t)n * HID;     // n*HID
    float* pooled = bufB + (size_t)n * HID;     // g*HID
    float* counts = pooled + (size_t)g * HID;   // g

    const int B = 256;
    const int gridN  = (n + B - 1) / B;
    const int gridE  = (e + B - 1) / B;
    const int gridNH = (n * HID + B - 1) / B;
    const int gridEW = (int)(((size_t)e * 64 + B - 1) / B);   // wave per edge
    const int gridNW = (int)(((size_t)n * 64 + B - 1) / B);   // wave per node
    const int gridT  = (n + 63) / 64;                          // gemm tiles

    hipMemsetAsync(pooled, 0, (size_t)(g * HID + g) * sizeof(float), stream);

    // norm precompute
    init_deg_k<<<gridN, B, 0, stream>>>(deg, n);
    deg_accum_k<<<gridE, B, 0, stream>>>(dst, deg, e);
    dinv_k<<<gridN, B, 0, stream>>>(deg, n);
    norm_k<<<gridE, B, 0, stream>>>(src, dst, deg, norm, e);

    // layer 1: t1 = x@W1 (bufA); agg into bufB; +b1, relu
    gemm_tile_k<FEAT><<<gridT, B, 0, stream>>>(x, W1, bufA, n);
    selfloop_k<<<gridNH, B, 0, stream>>>(bufA, deg, bufB, n);
    edge_scatter_k<<<gridEW, B, 0, stream>>>(bufA, src, dst, norm, bufB, e);
    bias_relu_k<<<gridNH, B, 0, stream>>>(bufB, b1, n);

    // layer 2: t2 = h1@W2 (bufA); agg into bufB; +b2, relu
    gemm_tile_k<HID><<<gridT, B, 0, stream>>>(bufB, W2, bufA, n);
    selfloop_k<<<gridNH, B, 0, stream>>>(bufA, deg, bufB, n);
    edge_scatter_k<<<gridEW, B, 0, stream>>>(bufA, src, dst, norm, bufB, e);
    bias_relu_k<<<gridNH, B, 0, stream>>>(bufB, b2, n);

    // heads
    head_k<<<gridNW, B, 0, stream>>>(bufB, Wa, ba, batch, (float*)d_out, pooled, counts, n);
    value_k<<<(g * 64 + B - 1) / B, B, 0, stream>>>(pooled, counts, Wc, bc, (float*)d_out + n, g);
}

// Round 3
// 1309.705 us; speedup vs baseline: 1.9021x; 1.4341x over previous
//
#include <hip/hip_runtime.h>
#include <math.h>

#define FEAT 128
#define HID  64

// ---------------- degree / norm ----------------

__global__ void init_deg_k(float* deg, int n) {
    int i = blockIdx.x * blockDim.x + threadIdx.x;
    if (i < n) deg[i] = 1.0f;   // self-loop contributes 1
}

__global__ void deg_accum_k(const int* __restrict__ dst, float* deg, int e) {
    int i = blockIdx.x * blockDim.x + threadIdx.x;
    if (i < e) atomicAdd(&deg[dst[i]], 1.0f);
}

__global__ void dinv_k(float* deg, int n) {
    int i = blockIdx.x * blockDim.x + threadIdx.x;
    if (i < n) deg[i] = 1.0f / sqrtf(deg[i]);   // deg >= 1 always
}

__global__ void norm_k(const int* __restrict__ src, const int* __restrict__ dst,
                       const float* __restrict__ dinv, float* __restrict__ norm, int e) {
    int i = blockIdx.x * blockDim.x + threadIdx.x;
    if (i < e) norm[i] = dinv[src[i]] * dinv[dst[i]];
}

// ---------------- dense transform: out[n,64] = X[n,K] @ W[K,64] ----------------

template<int K>
__global__ __launch_bounds__(256, 2) void gemm_tile_k(const float* __restrict__ X,
                                                      const float* __restrict__ W,
                                                      float* __restrict__ out, int n) {
    __shared__ float sX[64][36];
    __shared__ float sW[32][64];
    const int row0 = blockIdx.x * 64;
    const int t  = threadIdx.x;
    const int tx = t & 15;
    const int ty = t >> 4;

    float acc[4][4] = {};

    for (int k0 = 0; k0 < K; k0 += 32) {
        {
            int r = t >> 3;
            int f = (t & 7) * 4;
            int gr = row0 + r;
            float4 v = make_float4(0.f, 0.f, 0.f, 0.f);
            if (gr < n) v = *(const float4*)(X + (size_t)gr * K + k0 + f);
            *(float4*)&sX[r][f] = v;
            gr += 32;
            float4 v2 = make_float4(0.f, 0.f, 0.f, 0.f);
            if (gr < n) v2 = *(const float4*)(X + (size_t)gr * K + k0 + f);
            *(float4*)&sX[r + 32][f] = v2;
        }
        {
            int wr = t >> 4;
            int wc = (t & 15) * 4;
            *(float4*)&sW[wr][wc]      = *(const float4*)(W + (size_t)(k0 + wr) * HID + wc);
            *(float4*)&sW[wr + 16][wc] = *(const float4*)(W + (size_t)(k0 + wr + 16) * HID + wc);
        }
        __syncthreads();

#pragma unroll
        for (int k = 0; k < 32; k += 4) {
            float4 a[4], b[4];
#pragma unroll
            for (int i = 0; i < 4; i++) a[i] = *(float4*)&sX[ty * 4 + i][k];
#pragma unroll
            for (int j = 0; j < 4; j++) b[j] = *(float4*)&sW[k + j][tx * 4];
#pragma unroll
            for (int i = 0; i < 4; i++) {
                acc[i][0] = fmaf(a[i].x, b[0].x, acc[i][0]);
                acc[i][1] = fmaf(a[i].x, b[0].y, acc[i][1]);
                acc[i][2] = fmaf(a[i].x, b[0].z, acc[i][2]);
                acc[i][3] = fmaf(a[i].x, b[0].w, acc[i][3]);
                acc[i][0] = fmaf(a[i].y, b[1].x, acc[i][0]);
                acc[i][1] = fmaf(a[i].y, b[1].y, acc[i][1]);
                acc[i][2] = fmaf(a[i].y, b[1].z, acc[i][2]);
                acc[i][3] = fmaf(a[i].y, b[1].w, acc[i][3]);
                acc[i][0] = fmaf(a[i].z, b[2].x, acc[i][0]);
                acc[i][1] = fmaf(a[i].z, b[2].y, acc[i][1]);
                acc[i][2] = fmaf(a[i].z, b[2].z, acc[i][2]);
                acc[i][3] = fmaf(a[i].z, b[2].w, acc[i][3]);
                acc[i][0] = fmaf(a[i].w, b[3].x, acc[i][0]);
                acc[i][1] = fmaf(a[i].w, b[3].y, acc[i][1]);
                acc[i][2] = fmaf(a[i].w, b[3].z, acc[i][2]);
                acc[i][3] = fmaf(a[i].w, b[3].w, acc[i][3]);
            }
        }
        __syncthreads();
    }

#pragma unroll
    for (int i = 0; i < 4; i++) {
        int gr = row0 + ty * 4 + i;
        if (gr < n)
            *(float4*)(out + (size_t)gr * HID + tx * 4) =
                make_float4(acc[i][0], acc[i][1], acc[i][2], acc[i][3]);
    }
}

// ---------------- aggregation ----------------

__global__ void selfloop_k(const float* __restrict__ t, const float* __restrict__ dinv,
                           float* __restrict__ out, int n) {
    int i = blockIdx.x * blockDim.x + threadIdx.x;
    if (i < n * HID) {
        int node = i >> 6;
        float d = dinv[node];
        out[i] = t[i] * d * d;
    }
}

__global__ void edge_scatter_k(const float* __restrict__ t, const int* __restrict__ src,
                               const int* __restrict__ dst, const float* __restrict__ norm,
                               float* out, int e) {
    int gw   = (int)((blockIdx.x * (size_t)blockDim.x + threadIdx.x) >> 6);
    int lane = threadIdx.x & 63;
    if (gw >= e) return;
    int s = src[gw];
    int d = dst[gw];
    float w = norm[gw];
    float v = t[(size_t)s * HID + lane] * w;
    atomicAdd(&out[(size_t)d * HID + lane], v);
}

__global__ void bias_relu_k(float* h, const float* __restrict__ b, int n) {
    int i = blockIdx.x * blockDim.x + threadIdx.x;
    if (i < n * HID) h[i] = fmaxf(h[i] + b[i & 63], 0.0f);
}

// ---------------- heads ----------------
// Segmented pooling: batch is sorted, so each wave keeps a per-lane running
// sum for the current group and flushes ONE atomicAdd per group transition
// (~2 per wave) instead of one per node. Kills the 6.4M-atomics-into-4096-
// addresses serialization.

#define HCHUNK 256   // nodes per block

__global__ void head_k(const float* __restrict__ h, const float* __restrict__ Wa,
                       const float* __restrict__ ba, const int* __restrict__ batch,
                       float* __restrict__ logits, float* __restrict__ pooled,
                       float* __restrict__ counts, int n) {
    int start = blockIdx.x * HCHUNK;
    int end   = min(start + HCHUNK, n);
    int lane  = threadIdx.x & 63;
    int wave  = threadIdx.x >> 6;
    float wa  = Wa[lane];
    float ba0 = ba[0];

    float acc = 0.0f;
    int   curg = -1;
    int   cnt = 0;
    for (int i = start + wave; i < end; i += 4) {
        float v = h[(size_t)i * HID + lane];
        float p = v * wa;
#pragma unroll
        for (int off = 32; off > 0; off >>= 1) p += __shfl_down(p, off);
        if (lane == 0) logits[i] = p + ba0;
        int g = batch[i];
        if (g != curg) {
            if (curg >= 0) {
                atomicAdd(&pooled[curg * HID + lane], acc);
                if (lane == 0) atomicAdd(&counts[curg], (float)cnt);
            }
            curg = g; acc = 0.0f; cnt = 0;
        }
        acc += v; cnt++;
    }
    if (curg >= 0) {
        atomicAdd(&pooled[curg * HID + lane], acc);
        if (lane == 0) atomicAdd(&counts[curg], (float)cnt);
    }
}

__global__ void value_k(const float* __restrict__ pooled, const float* __restrict__ counts,
                        const float* __restrict__ Wc, const float* __restrict__ bc,
                        float* __restrict__ val, int g) {
    int gw   = (int)((blockIdx.x * (size_t)blockDim.x + threadIdx.x) >> 6);
    int lane = threadIdx.x & 63;
    if (gw >= g) return;
    float cnt = fmaxf(counts[gw], 1.0f);
    float p = (pooled[gw * HID + lane] / cnt) * Wc[lane];
#pragma unroll
    for (int off = 32; off > 0; off >>= 1) p += __shfl_down(p, off);
    if (lane == 0) val[gw] = p + bc[0];
}

extern "C" void kernel_launch(void* const* d_in, const int* in_sizes, int n_in,
                              void* d_out, int out_size, void* d_ws, size_t ws_size,
                              hipStream_t stream) {
    const float* x     = (const float*)d_in[0];
    const int*   ei    = (const int*)d_in[1];
    const int*   batch = (const int*)d_in[2];
    const float* W1    = (const float*)d_in[3];
    const float* b1    = (const float*)d_in[4];
    const float* W2    = (const float*)d_in[5];
    const float* b2    = (const float*)d_in[6];
    const float* Wa    = (const float*)d_in[7];
    const float* ba    = (const float*)d_in[8];
    const float* Wc    = (const float*)d_in[9];
    const float* bc    = (const float*)d_in[10];

    const int n = in_sizes[0] / FEAT;   // 100000
    const int e = in_sizes[1] / 2;      // 1600000
    const int g = out_size - n;         // 64
    const int* src = ei;
    const int* dst = ei + e;

    float* ws     = (float*)d_ws;
    float* deg    = ws;                         // n  (becomes dinv in place)
    float* norm   = deg + n;                    // e
    float* bufA   = norm + e;                   // n*HID
    float* bufB   = bufA + (size_t)n * HID;     // n*HID
    float* pooled = bufB + (size_t)n * HID;     // g*HID
    float* counts = pooled + (size_t)g * HID;   // g

    const int B = 256;
    const int gridN  = (n + B - 1) / B;
    const int gridE  = (e + B - 1) / B;
    const int gridNH = (n * HID + B - 1) / B;
    const int gridEW = (int)(((size_t)e * 64 + B - 1) / B);   // wave per edge
    const int gridT  = (n + 63) / 64;                          // gemm tiles
    const int gridH  = (n + HCHUNK - 1) / HCHUNK;

    hipMemsetAsync(pooled, 0, (size_t)(g * HID + g) * sizeof(float), stream);

    // norm precompute
    init_deg_k<<<gridN, B, 0, stream>>>(deg, n);
    deg_accum_k<<<gridE, B, 0, stream>>>(dst, deg, e);
    dinv_k<<<gridN, B, 0, stream>>>(deg, n);
    norm_k<<<gridE, B, 0, stream>>>(src, dst, deg, norm, e);

    // layer 1: t1 = x@W1 (bufA); agg into bufB; +b1, relu
    gemm_tile_k<FEAT><<<gridT, B, 0, stream>>>(x, W1, bufA, n);
    selfloop_k<<<gridNH, B, 0, stream>>>(bufA, deg, bufB, n);
    edge_scatter_k<<<gridEW, B, 0, stream>>>(bufA, src, dst, norm, bufB, e);
    bias_relu_k<<<gridNH, B, 0, stream>>>(bufB, b1, n);

    // layer 2: t2 = h1@W2 (bufA); agg into bufB; +b2, relu
    gemm_tile_k<HID><<<gridT, B, 0, stream>>>(bufB, W2, bufA, n);
    selfloop_k<<<gridNH, B, 0, stream>>>(bufA, deg, bufB, n);
    edge_scatter_k<<<gridEW, B, 0, stream>>>(bufA, src, dst, norm, bufB, e);
    bias_relu_k<<<gridNH, B, 0, stream>>>(bufB, b2, n);

    // heads
    head_k<<<gridH, B, 0, stream>>>(bufB, Wa, ba, batch, (float*)d_out, pooled, counts, n);
    value_k<<<(g * 64 + B - 1) / B, B, 0, stream>>>(pooled, counts, Wc, bc, (float*)d_out + n, g);
}

// Round 4
// 863.656 us; speedup vs baseline: 2.8844x; 1.5165x over previous
//
#include <hip/hip_runtime.h>
#include <math.h>

#define FEAT 128
#define HID  64

// ---------------- CSR build: histogram, scan, fill ----------------

__global__ void hist_k(const int* __restrict__ dst, int* hist, int e) {
    int i = blockIdx.x * blockDim.x + threadIdx.x;
    if (i < e) atomicAdd(&hist[dst[i]], 1);
}

__global__ void dinv_k(const int* __restrict__ hist, float* __restrict__ dinv, int n) {
    int i = blockIdx.x * blockDim.x + threadIdx.x;
    if (i < n) dinv[i] = 1.0f / sqrtf(1.0f + (float)hist[i]);   // self-loop adds 1
}

// per-block exclusive scan (Hillis-Steele in LDS); block sums to aux
__global__ void scan1_k(const int* __restrict__ hist, int* __restrict__ rowptr,
                        int* __restrict__ aux, int n) {
    __shared__ int s[256];
    int gid = blockIdx.x * 256 + threadIdx.x;
    int v = (gid < n) ? hist[gid] : 0;
    s[threadIdx.x] = v;
    __syncthreads();
    for (int off = 1; off < 256; off <<= 1) {
        int t = (threadIdx.x >= off) ? s[threadIdx.x - off] : 0;
        __syncthreads();
        s[threadIdx.x] += t;
        __syncthreads();
    }
    if (gid < n) rowptr[gid] = s[threadIdx.x] - v;          // exclusive
    if (threadIdx.x == 255) aux[blockIdx.x] = s[255];       // block total
}

__global__ void scan2_k(int* aux, int naux) {
    __shared__ int s[512];
    int v = (threadIdx.x < naux) ? aux[threadIdx.x] : 0;
    s[threadIdx.x] = v;
    __syncthreads();
    for (int off = 1; off < 512; off <<= 1) {
        int t = (threadIdx.x >= off) ? s[threadIdx.x - off] : 0;
        __syncthreads();
        s[threadIdx.x] += t;
        __syncthreads();
    }
    if (threadIdx.x < naux) aux[threadIdx.x] = s[threadIdx.x] - v;   // exclusive
}

__global__ void scan3_k(int* __restrict__ rowptr, int* __restrict__ pos,
                        const int* __restrict__ aux, int n, int e) {
    int i = blockIdx.x * 256 + threadIdx.x;
    if (i < n) {
        int v = rowptr[i] + aux[blockIdx.x];
        rowptr[i] = v;
        pos[i] = v;
        if (i == n - 1) rowptr[n] = e;
    }
}

__global__ void fill_k(const int* __restrict__ src, const int* __restrict__ dst,
                       int* pos, int* __restrict__ col, int e) {
    int i = blockIdx.x * blockDim.x + threadIdx.x;
    if (i < e) {
        int p = atomicAdd(&pos[dst[i]], 1);
        col[p] = src[i];
    }
}

// ---------------- dense transform: out[n,64] = (X[n,K] @ W[K,64]) * dinv[row] ----------------

template<int K>
__global__ __launch_bounds__(256, 2) void gemm_tile_k(const float* __restrict__ X,
                                                      const float* __restrict__ W,
                                                      const float* __restrict__ dinv,
                                                      float* __restrict__ out, int n) {
    __shared__ float sX[64][36];
    __shared__ float sW[32][64];
    const int row0 = blockIdx.x * 64;
    const int t  = threadIdx.x;
    const int tx = t & 15;
    const int ty = t >> 4;

    float acc[4][4] = {};

    for (int k0 = 0; k0 < K; k0 += 32) {
        {
            int r = t >> 3;
            int f = (t & 7) * 4;
            int gr = row0 + r;
            float4 v = make_float4(0.f, 0.f, 0.f, 0.f);
            if (gr < n) v = *(const float4*)(X + (size_t)gr * K + k0 + f);
            *(float4*)&sX[r][f] = v;
            gr += 32;
            float4 v2 = make_float4(0.f, 0.f, 0.f, 0.f);
            if (gr < n) v2 = *(const float4*)(X + (size_t)gr * K + k0 + f);
            *(float4*)&sX[r + 32][f] = v2;
        }
        {
            int wr = t >> 4;
            int wc = (t & 15) * 4;
            *(float4*)&sW[wr][wc]      = *(const float4*)(W + (size_t)(k0 + wr) * HID + wc);
            *(float4*)&sW[wr + 16][wc] = *(const float4*)(W + (size_t)(k0 + wr + 16) * HID + wc);
        }
        __syncthreads();

#pragma unroll
        for (int k = 0; k < 32; k += 4) {
            float4 a[4], b[4];
#pragma unroll
            for (int i = 0; i < 4; i++) a[i] = *(float4*)&sX[ty * 4 + i][k];
#pragma unroll
            for (int j = 0; j < 4; j++) b[j] = *(float4*)&sW[k + j][tx * 4];
#pragma unroll
            for (int i = 0; i < 4; i++) {
                acc[i][0] = fmaf(a[i].x, b[0].x, acc[i][0]);
                acc[i][1] = fmaf(a[i].x, b[0].y, acc[i][1]);
                acc[i][2] = fmaf(a[i].x, b[0].z, acc[i][2]);
                acc[i][3] = fmaf(a[i].x, b[0].w, acc[i][3]);
                acc[i][0] = fmaf(a[i].y, b[1].x, acc[i][0]);
                acc[i][1] = fmaf(a[i].y, b[1].y, acc[i][1]);
                acc[i][2] = fmaf(a[i].y, b[1].z, acc[i][2]);
                acc[i][3] = fmaf(a[i].y, b[1].w, acc[i][3]);
                acc[i][0] = fmaf(a[i].z, b[2].x, acc[i][0]);
                acc[i][1] = fmaf(a[i].z, b[2].y, acc[i][1]);
                acc[i][2] = fmaf(a[i].z, b[2].z, acc[i][2]);
                acc[i][3] = fmaf(a[i].z, b[2].w, acc[i][3]);
                acc[i][0] = fmaf(a[i].w, b[3].x, acc[i][0]);
                acc[i][1] = fmaf(a[i].w, b[3].y, acc[i][1]);
                acc[i][2] = fmaf(a[i].w, b[3].z, acc[i][2]);
                acc[i][3] = fmaf(a[i].w, b[3].w, acc[i][3]);
            }
        }
        __syncthreads();
    }

#pragma unroll
    for (int i = 0; i < 4; i++) {
        int gr = row0 + ty * 4 + i;
        if (gr < n) {
            float sc = dinv[gr];
            *(float4*)(out + (size_t)gr * HID + tx * 4) =
                make_float4(acc[i][0] * sc, acc[i][1] * sc, acc[i][2] * sc, acc[i][3] * sc);
        }
    }
}

// ---------------- CSR gather aggregation (fused selfloop + bias + relu) ----------------
// h[d] = relu( dinv[d] * (tS[d] + sum_{e in in(d)} tS[col[e]]) + b )
// where tS = (X@W)*dinv from the gemm epilogue. One wave per node, lane=feature.

__global__ void gather_k(const float* __restrict__ tS, const int* __restrict__ rowptr,
                         const int* __restrict__ col, const float* __restrict__ dinv,
                         const float* __restrict__ b, float* __restrict__ out, int n) {
    int node = (int)((blockIdx.x * (size_t)blockDim.x + threadIdx.x) >> 6);
    int lane = threadIdx.x & 63;
    if (node >= n) return;
    int beg = rowptr[node], end = rowptr[node + 1];
    const float* tl = tS + lane;
    float acc = tl[(size_t)node * HID];   // self-loop term
    int e = beg;
    for (; e + 4 <= end; e += 4) {
        int s0 = col[e], s1 = col[e + 1], s2 = col[e + 2], s3 = col[e + 3];
        float v0 = tl[(size_t)s0 * HID];
        float v1 = tl[(size_t)s1 * HID];
        float v2 = tl[(size_t)s2 * HID];
        float v3 = tl[(size_t)s3 * HID];
        acc += (v0 + v1) + (v2 + v3);
    }
    for (; e < end; ++e) acc += tl[(size_t)col[e] * HID];
    out[(size_t)node * HID + lane] = fmaxf(fmaf(dinv[node], acc, b[lane]), 0.0f);
}

// ---------------- heads ----------------

__global__ void pool_k(const float* __restrict__ h, const int* __restrict__ batch,
                       float* __restrict__ pooled, float* __restrict__ counts, int n) {
    int lane = threadIdx.x & 63;
    int wave = threadIdx.x >> 6;
    int start = blockIdx.x * 64 + wave * 16;
    int end   = min(start + 16, n);
    if (start >= end) return;
    float acc = 0.0f;
    int curg = -1, cnt = 0;
    for (int i = start; i < end; i++) {
        int g = batch[i];
        if (g != curg) {
            if (curg >= 0) {
                atomicAdd(&pooled[curg * HID + lane], acc);
                if (lane == 0) atomicAdd(&counts[curg], (float)cnt);
            }
            curg = g; acc = 0.0f; cnt = 0;
        }
        acc += h[(size_t)i * HID + lane];
        cnt++;
    }
    atomicAdd(&pooled[curg * HID + lane], acc);
    if (lane == 0) atomicAdd(&counts[curg], (float)cnt);
}

__global__ void logits_k(const float* __restrict__ h, const float* __restrict__ Wa,
                         const float* __restrict__ ba, float* __restrict__ out, int n) {
    __shared__ float sWa[HID];
    if (threadIdx.x < HID) sWa[threadIdx.x] = Wa[threadIdx.x];
    __syncthreads();
    int i = blockIdx.x * blockDim.x + threadIdx.x;
    if (i >= n) return;
    const float4* hp = (const float4*)(h + (size_t)i * HID);
    float acc = 0.0f;
#pragma unroll
    for (int k = 0; k < HID / 4; k++) {
        float4 v = hp[k];
        acc = fmaf(v.x, sWa[4 * k + 0],
              fmaf(v.y, sWa[4 * k + 1],
              fmaf(v.z, sWa[4 * k + 2],
              fmaf(v.w, sWa[4 * k + 3], acc))));
    }
    out[i] = acc + ba[0];
}

__global__ void value_k(const float* __restrict__ pooled, const float* __restrict__ counts,
                        const float* __restrict__ Wc, const float* __restrict__ bc,
                        float* __restrict__ val, int g) {
    int gw   = (int)((blockIdx.x * (size_t)blockDim.x + threadIdx.x) >> 6);
    int lane = threadIdx.x & 63;
    if (gw >= g) return;
    float cnt = fmaxf(counts[gw], 1.0f);
    float p = (pooled[gw * HID + lane] / cnt) * Wc[lane];
#pragma unroll
    for (int off = 32; off > 0; off >>= 1) p += __shfl_down(p, off);
    if (lane == 0) val[gw] = p + bc[0];
}

extern "C" void kernel_launch(void* const* d_in, const int* in_sizes, int n_in,
                              void* d_out, int out_size, void* d_ws, size_t ws_size,
                              hipStream_t stream) {
    const float* x     = (const float*)d_in[0];
    const int*   ei    = (const int*)d_in[1];
    const int*   batch = (const int*)d_in[2];
    const float* W1    = (const float*)d_in[3];
    const float* b1    = (const float*)d_in[4];
    const float* W2    = (const float*)d_in[5];
    const float* b2    = (const float*)d_in[6];
    const float* Wa    = (const float*)d_in[7];
    const float* ba    = (const float*)d_in[8];
    const float* Wc    = (const float*)d_in[9];
    const float* bc    = (const float*)d_in[10];

    const int n = in_sizes[0] / FEAT;   // 100000
    const int e = in_sizes[1] / 2;      // 1600000
    const int g = out_size - n;         // 64
    const int* src = ei;
    const int* dst = ei + e;

    // workspace layout
    float* ws     = (float*)d_ws;
    float* dinv   = ws;                              // n
    float* bufA   = dinv + n;                        // n*HID  (tS)
    float* bufB   = bufA + (size_t)n * HID;          // n*HID  (h)
    int*   hist   = (int*)(bufB + (size_t)n * HID);  // n (reused as pos)
    float* pooled = (float*)(hist + n);              // g*HID
    float* counts = pooled + (size_t)g * HID;        // g
    int*   rowptr = (int*)(counts + g);              // n+1
    int*   aux    = rowptr + n + 1;                  // 512
    int*   col    = aux + 512;                       // e

    const int B = 256;
    const int nbN = (n + B - 1) / B;        // 391
    const int nbE = (e + B - 1) / B;        // 6250
    const int gridT = (n + 63) / 64;        // gemm tiles
    const int gridG = (int)(((size_t)n * 64 + B - 1) / B);   // wave per node
    const int gridP = (n + 63) / 64;        // pool blocks

    // zero hist + pooled + counts (contiguous)
    hipMemsetAsync(hist, 0, (size_t)(n + g * HID + g) * sizeof(int), stream);

    // CSR build + dinv
    hist_k<<<nbE, B, 0, stream>>>(dst, hist, e);
    dinv_k<<<nbN, B, 0, stream>>>(hist, dinv, n);
    scan1_k<<<nbN, B, 0, stream>>>(hist, rowptr, aux, n);
    scan2_k<<<1, 512, 0, stream>>>(aux, nbN);
    scan3_k<<<nbN, B, 0, stream>>>(rowptr, hist /*pos*/, aux, n, e);
    fill_k<<<nbE, B, 0, stream>>>(src, dst, hist /*pos*/, col, e);

    // layer 1
    gemm_tile_k<FEAT><<<gridT, B, 0, stream>>>(x, W1, dinv, bufA, n);
    gather_k<<<gridG, B, 0, stream>>>(bufA, rowptr, col, dinv, b1, bufB, n);

    // layer 2
    gemm_tile_k<HID><<<gridT, B, 0, stream>>>(bufB, W2, dinv, bufA, n);
    gather_k<<<gridG, B, 0, stream>>>(bufA, rowptr, col, dinv, b2, bufB, n);

    // heads
    pool_k<<<gridP, B, 0, stream>>>(bufB, batch, pooled, counts, n);
    logits_k<<<nbN, B, 0, stream>>>(bufB, Wa, ba, (float*)d_out, n);
    value_k<<<(g * 64 + B - 1) / B, B, 0, stream>>>(pooled, counts, Wc, bc, (float*)d_out + n, g);
}

// Round 5
// 536.794 us; speedup vs baseline: 4.6408x; 1.6089x over previous
//
#include <hip/hip_runtime.h>
#include <math.h>

#define FEAT 128
#define HID  64

// ---------------- CSR build: histogram, scan, fill ----------------

__global__ void hist_k(const int* __restrict__ dst, int* hist, int e) {
    int i = blockIdx.x * blockDim.x + threadIdx.x;
    if (i < e) atomicAdd(&hist[dst[i]], 1);
}

__global__ void dinv_k(const int* __restrict__ hist, float* __restrict__ dinv, int n) {
    int i = blockIdx.x * blockDim.x + threadIdx.x;
    if (i < n) dinv[i] = 1.0f / sqrtf(1.0f + (float)hist[i]);   // self-loop adds 1
}

__global__ void scan1_k(const int* __restrict__ hist, int* __restrict__ rowptr,
                        int* __restrict__ aux, int n) {
    __shared__ int s[256];
    int gid = blockIdx.x * 256 + threadIdx.x;
    int v = (gid < n) ? hist[gid] : 0;
    s[threadIdx.x] = v;
    __syncthreads();
    for (int off = 1; off < 256; off <<= 1) {
        int t = (threadIdx.x >= off) ? s[threadIdx.x - off] : 0;
        __syncthreads();
        s[threadIdx.x] += t;
        __syncthreads();
    }
    if (gid < n) rowptr[gid] = s[threadIdx.x] - v;          // exclusive
    if (threadIdx.x == 255) aux[blockIdx.x] = s[255];       // block total
}

__global__ void scan2_k(int* aux, int naux) {
    __shared__ int s[512];
    int v = (threadIdx.x < naux) ? aux[threadIdx.x] : 0;
    s[threadIdx.x] = v;
    __syncthreads();
    for (int off = 1; off < 512; off <<= 1) {
        int t = (threadIdx.x >= off) ? s[threadIdx.x - off] : 0;
        __syncthreads();
        s[threadIdx.x] += t;
        __syncthreads();
    }
    if (threadIdx.x < naux) aux[threadIdx.x] = s[threadIdx.x] - v;   // exclusive
}

__global__ void scan3_k(int* __restrict__ rowptr, int* __restrict__ pos,
                        const int* __restrict__ aux, int n, int e) {
    int i = blockIdx.x * 256 + threadIdx.x;
    if (i < n) {
        int v = rowptr[i] + aux[blockIdx.x];
        rowptr[i] = v;
        pos[i] = v;
        if (i == n - 1) rowptr[n] = e;
    }
}

__global__ void fill_k(const int* __restrict__ src, const int* __restrict__ dst,
                       int* pos, int* __restrict__ col, int e) {
    int i = blockIdx.x * blockDim.x + threadIdx.x;
    if (i < e) {
        int p = atomicAdd(&pos[dst[i]], 1);
        col[p] = src[i];
    }
}

// ---------------- dense transform: out[n,64] = (X[n,K] @ W[K,64]) * dinv[row] ----------------
// Single-phase: each block's 64-row X tile is one CONTIGUOUS 32KB (K=128) /
// 16KB (K=64) region of row-major X — load it whole with 4KB-per-instruction
// fully-coalesced float4 streams. Full W staged likewise (contiguous,
// L2-broadcast across blocks). One barrier, then a flat K loop.
// LDS pad K+4 keeps compute-side reads at <=2-way bank alias (free).

template<int K>
__global__ __launch_bounds__(256, 2) void gemm_tile_k(const float* __restrict__ X,
                                                      const float* __restrict__ W,
                                                      const float* __restrict__ dinv,
                                                      float* __restrict__ out, int n) {
    __shared__ float sX[64][K + 4];
    __shared__ float sW[K][64];
    const int row0 = blockIdx.x * 64;
    const int t  = threadIdx.x;
    const int tx = t & 15;
    const int ty = t >> 4;
    constexpr int KSH = (K == 128) ? 7 : 6;

    // stage X: contiguous 64*K floats starting at X + row0*K
    const float* xb = X + (size_t)row0 * K;
#pragma unroll
    for (int it = 0; it < K / 16; ++it) {
        int fl = it * 1024 + t * 4;       // flat float index within tile
        int r  = fl >> KSH;
        int k  = fl & (K - 1);
        float4 v = make_float4(0.f, 0.f, 0.f, 0.f);
        if (row0 + r < n) v = *(const float4*)(xb + fl);
        *(float4*)&sX[r][k] = v;
    }
    // stage W: contiguous K*64 floats
#pragma unroll
    for (int it = 0; it < K / 16; ++it) {
        int fl = it * 1024 + t * 4;
        *(float4*)&sW[fl >> 6][fl & 63] = *(const float4*)(W + fl);
    }
    __syncthreads();

    float acc[4][4] = {};
#pragma unroll 8
    for (int k = 0; k < K; k += 4) {
        float4 a[4], b[4];
#pragma unroll
        for (int i = 0; i < 4; i++) a[i] = *(float4*)&sX[ty * 4 + i][k];
#pragma unroll
        for (int j = 0; j < 4; j++) b[j] = *(float4*)&sW[k + j][tx * 4];
#pragma unroll
        for (int i = 0; i < 4; i++) {
            acc[i][0] = fmaf(a[i].x, b[0].x, acc[i][0]);
            acc[i][1] = fmaf(a[i].x, b[0].y, acc[i][1]);
            acc[i][2] = fmaf(a[i].x, b[0].z, acc[i][2]);
            acc[i][3] = fmaf(a[i].x, b[0].w, acc[i][3]);
            acc[i][0] = fmaf(a[i].y, b[1].x, acc[i][0]);
            acc[i][1] = fmaf(a[i].y, b[1].y, acc[i][1]);
            acc[i][2] = fmaf(a[i].y, b[1].z, acc[i][2]);
            acc[i][3] = fmaf(a[i].y, b[1].w, acc[i][3]);
            acc[i][0] = fmaf(a[i].z, b[2].x, acc[i][0]);
            acc[i][1] = fmaf(a[i].z, b[2].y, acc[i][1]);
            acc[i][2] = fmaf(a[i].z, b[2].z, acc[i][2]);
            acc[i][3] = fmaf(a[i].z, b[2].w, acc[i][3]);
            acc[i][0] = fmaf(a[i].w, b[3].x, acc[i][0]);
            acc[i][1] = fmaf(a[i].w, b[3].y, acc[i][1]);
            acc[i][2] = fmaf(a[i].w, b[3].z, acc[i][2]);
            acc[i][3] = fmaf(a[i].w, b[3].w, acc[i][3]);
        }
    }

#pragma unroll
    for (int i = 0; i < 4; i++) {
        int gr = row0 + ty * 4 + i;
        if (gr < n) {
            float sc = dinv[gr];
            *(float4*)(out + (size_t)gr * HID + tx * 4) =
                make_float4(acc[i][0] * sc, acc[i][1] * sc, acc[i][2] * sc, acc[i][3] * sc);
        }
    }
}

// ---------------- CSR gather aggregation (fused selfloop + bias + relu) ----------------

__global__ void gather_k(const float* __restrict__ tS, const int* __restrict__ rowptr,
                         const int* __restrict__ col, const float* __restrict__ dinv,
                         const float* __restrict__ b, float* __restrict__ out, int n) {
    int node = (int)((blockIdx.x * (size_t)blockDim.x + threadIdx.x) >> 6);
    int lane = threadIdx.x & 63;
    if (node >= n) return;
    int beg = rowptr[node], end = rowptr[node + 1];
    const float* tl = tS + lane;
    float acc = tl[(size_t)node * HID];   // self-loop term
    int e = beg;
    for (; e + 4 <= end; e += 4) {
        int s0 = col[e], s1 = col[e + 1], s2 = col[e + 2], s3 = col[e + 3];
        float v0 = tl[(size_t)s0 * HID];
        float v1 = tl[(size_t)s1 * HID];
        float v2 = tl[(size_t)s2 * HID];
        float v3 = tl[(size_t)s3 * HID];
        acc += (v0 + v1) + (v2 + v3);
    }
    for (; e < end; ++e) acc += tl[(size_t)col[e] * HID];
    out[(size_t)node * HID + lane] = fmaxf(fmaf(dinv[node], acc, b[lane]), 0.0f);
}

// ---------------- heads ----------------

__global__ void pool_k(const float* __restrict__ h, const int* __restrict__ batch,
                       float* __restrict__ pooled, float* __restrict__ counts, int n) {
    int lane = threadIdx.x & 63;
    int wave = threadIdx.x >> 6;
    int start = blockIdx.x * 64 + wave * 16;
    int end   = min(start + 16, n);
    if (start >= end) return;
    float acc = 0.0f;
    int curg = -1, cnt = 0;
    for (int i = start; i < end; i++) {
        int g = batch[i];
        if (g != curg) {
            if (curg >= 0) {
                atomicAdd(&pooled[curg * HID + lane], acc);
                if (lane == 0) atomicAdd(&counts[curg], (float)cnt);
            }
            curg = g; acc = 0.0f; cnt = 0;
        }
        acc += h[(size_t)i * HID + lane];
        cnt++;
    }
    atomicAdd(&pooled[curg * HID + lane], acc);
    if (lane == 0) atomicAdd(&counts[curg], (float)cnt);
}

__global__ void logits_k(const float* __restrict__ h, const float* __restrict__ Wa,
                         const float* __restrict__ ba, float* __restrict__ out, int n) {
    __shared__ float sWa[HID];
    if (threadIdx.x < HID) sWa[threadIdx.x] = Wa[threadIdx.x];
    __syncthreads();
    int i = blockIdx.x * blockDim.x + threadIdx.x;
    if (i >= n) return;
    const float4* hp = (const float4*)(h + (size_t)i * HID);
    float acc = 0.0f;
#pragma unroll
    for (int k = 0; k < HID / 4; k++) {
        float4 v = hp[k];
        acc = fmaf(v.x, sWa[4 * k + 0],
              fmaf(v.y, sWa[4 * k + 1],
              fmaf(v.z, sWa[4 * k + 2],
              fmaf(v.w, sWa[4 * k + 3], acc))));
    }
    out[i] = acc + ba[0];
}

__global__ void value_k(const float* __restrict__ pooled, const float* __restrict__ counts,
                        const float* __restrict__ Wc, const float* __restrict__ bc,
                        float* __restrict__ val, int g) {
    int gw   = (int)((blockIdx.x * (size_t)blockDim.x + threadIdx.x) >> 6);
    int lane = threadIdx.x & 63;
    if (gw >= g) return;
    float cnt = fmaxf(counts[gw], 1.0f);
    float p = (pooled[gw * HID + lane] / cnt) * Wc[lane];
#pragma unroll
    for (int off = 32; off > 0; off >>= 1) p += __shfl_down(p, off);
    if (lane == 0) val[gw] = p + bc[0];
}

extern "C" void kernel_launch(void* const* d_in, const int* in_sizes, int n_in,
                              void* d_out, int out_size, void* d_ws, size_t ws_size,
                              hipStream_t stream) {
    const float* x     = (const float*)d_in[0];
    const int*   ei    = (const int*)d_in[1];
    const int*   batch = (const int*)d_in[2];
    const float* W1    = (const float*)d_in[3];
    const float* b1    = (const float*)d_in[4];
    const float* W2    = (const float*)d_in[5];
    const float* b2    = (const float*)d_in[6];
    const float* Wa    = (const float*)d_in[7];
    const float* ba    = (const float*)d_in[8];
    const float* Wc    = (const float*)d_in[9];
    const float* bc    = (const float*)d_in[10];

    const int n = in_sizes[0] / FEAT;   // 100000
    const int e = in_sizes[1] / 2;      // 1600000
    const int g = out_size - n;         // 64
    const int* src = ei;
    const int* dst = ei + e;

    // workspace layout
    float* ws     = (float*)d_ws;
    float* dinv   = ws;                              // n
    float* bufA   = dinv + n;                        // n*HID  (tS)
    float* bufB   = bufA + (size_t)n * HID;          // n*HID  (h)
    int*   hist   = (int*)(bufB + (size_t)n * HID);  // n (reused as pos)
    float* pooled = (float*)(hist + n);              // g*HID
    float* counts = pooled + (size_t)g * HID;        // g
    int*   rowptr = (int*)(counts + g);              // n+1
    int*   aux    = rowptr + n + 1;                  // 512
    int*   col    = aux + 512;                       // e

    const int B = 256;
    const int nbN = (n + B - 1) / B;        // 391
    const int nbE = (e + B - 1) / B;        // 6250
    const int gridT = (n + 63) / 64;        // gemm tiles
    const int gridG = (int)(((size_t)n * 64 + B - 1) / B);   // wave per node
    const int gridP = (n + 63) / 64;        // pool blocks

    // zero hist + pooled + counts (contiguous)
    hipMemsetAsync(hist, 0, (size_t)(n + g * HID + g) * sizeof(int), stream);

    // CSR build + dinv
    hist_k<<<nbE, B, 0, stream>>>(dst, hist, e);
    dinv_k<<<nbN, B, 0, stream>>>(hist, dinv, n);
    scan1_k<<<nbN, B, 0, stream>>>(hist, rowptr, aux, n);
    scan2_k<<<1, 512, 0, stream>>>(aux, nbN);
    scan3_k<<<nbN, B, 0, stream>>>(rowptr, hist /*pos*/, aux, n, e);
    fill_k<<<nbE, B, 0, stream>>>(src, dst, hist /*pos*/, col, e);

    // layer 1
    gemm_tile_k<FEAT><<<gridT, B, 0, stream>>>(x, W1, dinv, bufA, n);
    gather_k<<<gridG, B, 0, stream>>>(bufA, rowptr, col, dinv, b1, bufB, n);

    // layer 2
    gemm_tile_k<HID><<<gridT, B, 0, stream>>>(bufB, W2, dinv, bufA, n);
    gather_k<<<gridG, B, 0, stream>>>(bufA, rowptr, col, dinv, b2, bufB, n);

    // heads
    pool_k<<<gridP, B, 0, stream>>>(bufB, batch, pooled, counts, n);
    logits_k<<<nbN, B, 0, stream>>>(bufB, Wa, ba, (float*)d_out, n);
    value_k<<<(g * 64 + B - 1) / B, B, 0, stream>>>(pooled, counts, Wc, bc, (float*)d_out + n, g);
}